// Round 1
// baseline (2416.079 us; speedup 1.0000x reference)
//
#include <hip/hip_runtime.h>

#define B_   8192
#define T_   406
#define D_   10
#define P_   64
#define NC_  16          // K-chunks
#define TPC_ 26          // t per chunk (last chunk 16)
#define NT2_ 203         // total t-pairs (subtiles)

// output section offsets (floats), in reference return order
#define OUT_SEQ   0
#define OUT_IN    (B_*T_*D_)                         // 33259520
#define OUT_DIST  (2*B_*T_*D_)                       // 66519040
#define OUT_IDX   (2*B_*T_*D_ + B_*P_)
#define OUT_LAB   (2*B_*T_*D_ + B_*P_ + B_)
#define OUT_MASK  (2*B_*T_*D_ + B_*P_ + 2*B_)

// workspace offsets (floats)
#define WS_BX    0
#define WS_CP2   (NT2_*64*20)                        // 259840
#define WS_PART  (WS_CP2 + NT2_*64*2)                // 285824  (16B aligned)

typedef __attribute__((address_space(3))) unsigned int  lds_uint;
typedef __attribute__((address_space(1))) unsigned int  glb_uint;

__device__ __forceinline__ void gl_lds16(const float* g, float* l) {
    // async global->LDS, 16B/lane; LDS dest = wave-uniform base + lane*16
    __builtin_amdgcn_global_load_lds((const glb_uint*)g, (lds_uint*)l, 16, 0, 0);
}

// ---------------- kernel 1: prototype prep ----------------
// bx[t2][p][k] = -2*c[p][2*t2*10 + k]  (k<20), cp2[t2][p][km] = sum_d c[p][2t2+km][d]^2
__global__ void k1_prep(const float* __restrict__ protos,
                        float* __restrict__ bx, float* __restrict__ cp2) {
    int tid = blockIdx.x * 256 + threadIdx.x;
    if (tid >= NT2_ * 64) return;
    int t2 = tid >> 6;
    int p  = tid & 63;
    const float* src = protos + p * (T_ * D_) + t2 * 20;
    float v[20];
#pragma unroll
    for (int q = 0; q < 5; q++) *(float4*)&v[4*q] = *(const float4*)(src + 4*q);
    float s0 = 0.f, s1 = 0.f;
#pragma unroll
    for (int d = 0; d < 10; d++) { s0 += v[d]*v[d]; s1 += v[10+d]*v[10+d]; }
    float* dst = bx + (t2 * 64 + p) * 20;
#pragma unroll
    for (int q = 0; q < 5; q++) {
        float4 w = *(float4*)&v[4*q];
        w.x = -2.f*w.x; w.y = -2.f*w.y; w.z = -2.f*w.z; w.w = -2.f*w.w;
        *(float4*)(dst + 4*q) = w;
    }
    cp2[t2*128 + 2*p]     = s0;
    cp2[t2*128 + 2*p + 1] = s1;
}

// ---------------- kernel 2: main distance GEMM + fused copies ----------------
// grid 1024: blockIdx = bg*16 + c; 128 rows/block, chunk c covers t [c*26, c*26+26)
__global__ __launch_bounds__(256, 4) void k2_dist(
    const float* __restrict__ x, const float* __restrict__ mask,
    const float* __restrict__ bx, const float* __restrict__ cp2,
    float* __restrict__ partial, float* __restrict__ out_in,
    float* __restrict__ out_mask)
{
    __shared__ __align__(16) float Xs[2][2560];   // [128 rows][20]
    __shared__ __align__(16) float Bs[2][1280];   // [64 p][20]
    __shared__ __align__(16) float Ms[2][256];    // [128 rows][2]
    __shared__ __align__(16) float Cs[2][128];    // [64 p][2]

    const int tid  = threadIdx.x;
    const int wave = tid >> 6;
    const int lane = tid & 63;
    const int li   = lane >> 3;   // row sub-index (8 groups, broadcast over lj)
    const int lj   = lane & 7;    // p sub-index (consecutive lanes -> consecutive p)

    const int c  = blockIdx.x & 15;
    const int bg = blockIdx.x >> 4;
    const int rowBase = bg * 128;
    const int tBegin  = c * TPC_;
    const int tCnt    = (T_ - tBegin < TPC_) ? (T_ - tBegin) : TPC_;
    const int nsub    = tCnt >> 1;

    float acc[4][8];
    float sx[4];
#pragma unroll
    for (int r = 0; r < 4; r++) {
        sx[r] = 0.f;
#pragma unroll
        for (int j = 0; j < 8; j++) acc[r][j] = 0.f;
    }

    auto stage = [&](int buf, int st) {
        const int t0 = tBegin + 2 * st;
        const int t2 = t0 >> 1;
        // X tile: 2560 floats = 10 segs of 1KB (wave-strided)
#pragma unroll
        for (int s2 = 0; s2 < 3; s2++) {
            int s = wave + 4 * s2;
            if (s < 10) {
                int f   = s * 256 + lane * 4;
                int row = f / 20, kk = f % 20;
                gl_lds16(x + (rowBase + row) * (T_ * D_) + t0 * D_ + kk,
                         &Xs[buf][s * 256]);
            }
        }
        // B tile: 1280 floats = 5 segs (blob is linear: t2*1280 + f)
#pragma unroll
        for (int s2 = 0; s2 < 2; s2++) {
            int s = wave + 4 * s2;
            if (s < 5) {
                int f = s * 256 + lane * 4;
                gl_lds16(bx + t2 * 1280 + f, &Bs[buf][s * 256]);
            }
        }
        if (tid < 128) {
            const float2 m = *(const float2*)(mask + (rowBase + tid) * T_ + t0);
            *(float2*)&Ms[buf][tid * 2] = m;
            *(float2*)(out_mask + (rowBase + tid) * T_ + t0) = m;   // fused mask copy
        } else {
            int i = tid - 128;
            Cs[buf][i] = cp2[t2 * 128 + i];
        }
    };

    auto computeTile = [&](int buf) {
        float2 Mf[4], Cf[8];
#pragma unroll
        for (int r = 0; r < 4; r++)
            Mf[r] = *(const float2*)&Ms[buf][(wave * 32 + li + 8 * r) * 2];
#pragma unroll
        for (int j = 0; j < 8; j++)
            Cf[j] = *(const float2*)&Cs[buf][(lj + 8 * j) * 2];
#pragma unroll
        for (int g = 0; g < 5; g++) {
            float4 Bf[8], Af[4];
#pragma unroll
            for (int j = 0; j < 8; j++)
                Bf[j] = *(const float4*)&Bs[buf][(lj + 8 * j) * 20 + 4 * g];
#pragma unroll
            for (int r = 0; r < 4; r++)
                Af[r] = *(const float4*)&Xs[buf][(wave * 32 + li + 8 * r) * 20 + 4 * g];
#pragma unroll
            for (int e = 0; e < 4; e++) {
                const int k = 4 * g + e;     // compile-time after unroll
#pragma unroll
                for (int r = 0; r < 4; r++) {
                    float m = (k < 10) ? Mf[r].x : Mf[r].y;
                    float a = ((const float*)&Af[r])[e] * m;
                    sx[r] += a * a;          // mask binary: (mx)^2 == m*x^2
#pragma unroll
                    for (int j = 0; j < 8; j++)
                        acc[r][j] += a * ((const float*)&Bf[j])[e];
                }
            }
        }
        // sq_p part: acc += m[t] * cp2[p][t]
#pragma unroll
        for (int r = 0; r < 4; r++) {
#pragma unroll
            for (int j = 0; j < 8; j++) {
                acc[r][j] += Mf[r].x * Cf[j].x;
                acc[r][j] += Mf[r].y * Cf[j].y;
            }
        }
    };

    auto xcopy = [&](int buf, int st) {
        const int t0 = tBegin + 2 * st;
#pragma unroll
        for (int i2 = 0; i2 < 3; i2++) {
            int i = tid + 256 * i2;
            if (i < 640) {
                int f = i * 4;
                int row = f / 20, kk = f % 20;
                *(float4*)(out_in + (rowBase + row) * (T_ * D_) + t0 * D_ + kk) =
                    *(const float4*)&Xs[buf][f];
            }
        }
    };

    stage(0, 0);
    for (int st = 0; st < nsub; ++st) {
        const int buf = st & 1;
        __syncthreads();                       // staged data for st ready; buf^1 free
        if (st + 1 < nsub) stage(buf ^ 1, st + 1);
        computeTile(buf);
        xcopy(buf, st);                        // fused input_seq copy from LDS
    }

#pragma unroll
    for (int r = 0; r < 4; r++) {
        int row = rowBase + wave * 32 + li + 8 * r;
#pragma unroll
        for (int j = 0; j < 8; j++)
            partial[c * (B_ * P_) + row * P_ + lj + 8 * j] = acc[r][j] + sx[r];
    }
}

// ---------------- kernel 3: reduce + argmin + gather + scalar outputs ----------------
__global__ __launch_bounds__(256) void k3_fin(
    const float* __restrict__ partial, const float* __restrict__ protos,
    const int* __restrict__ label, float* __restrict__ out)
{
    __shared__ int sidx[4];
    const int tid = threadIdx.x, wave = tid >> 6, lane = tid & 63;
    const int b = blockIdx.x * 4 + wave;

    float v = 0.f;
#pragma unroll
    for (int cc = 0; cc < NC_; cc++) v += partial[cc * (B_ * P_) + b * 64 + lane];
    out[OUT_DIST + b * 64 + lane] = v;

    // 64-lane argmin, first-index tie-break (matches np.argmin)
    float bv = v; int bi = lane;
#pragma unroll
    for (int off = 32; off >= 1; off >>= 1) {
        float ov = __shfl_xor(bv, off, 64);
        int   oi = __shfl_xor(bi, off, 64);
        if (ov < bv || (ov == bv && oi < bi)) { bv = ov; bi = oi; }
    }
    if (lane == 0) {
        sidx[wave] = bi;
        out[OUT_IDX + b] = (float)bi;
        out[OUT_LAB + b] = (float)label[b];
    }
    __syncthreads();
    // gather prototypes[idx] -> output_seq (proto footprint 1MB -> L2 resident)
#pragma unroll
    for (int w2 = 0; w2 < 4; w2++) {
        const int bb = blockIdx.x * 4 + w2;
        const float* src = protos + sidx[w2] * (T_ * D_);
        float* dst = out + OUT_SEQ + (size_t)bb * (T_ * D_);
        for (int i = tid; i < 1015; i += 256)
            *(float4*)(dst + 4 * i) = *(const float4*)(src + 4 * i);
    }
}

extern "C" void kernel_launch(void* const* d_in, const int* in_sizes, int n_in,
                              void* d_out, int out_size, void* d_ws, size_t ws_size,
                              hipStream_t stream) {
    const float* x      = (const float*)d_in[0];
    const int*   label  = (const int*)d_in[1];
    const float* mask   = (const float*)d_in[2];
    const float* protos = (const float*)d_in[3];
    float* out = (float*)d_out;
    float* ws  = (float*)d_ws;

    float* bx      = ws + WS_BX;
    float* cp2     = ws + WS_CP2;
    float* partial = ws + WS_PART;   // NC_*B_*P_ floats = 33.5 MB

    hipLaunchKernelGGL(k1_prep, dim3((NT2_ * 64 + 255) / 256), dim3(256), 0, stream,
                       protos, bx, cp2);
    hipLaunchKernelGGL(k2_dist, dim3(64 * NC_), dim3(256), 0, stream,
                       x, mask, bx, cp2, partial, out + OUT_IN, out + OUT_MASK);
    hipLaunchKernelGGL(k3_fin, dim3(B_ / 4), dim3(256), 0, stream,
                       partial, protos, label, out);
}

// Round 2
// 448.206 us; speedup vs baseline: 5.3906x; 5.3906x over previous
//
#include <hip/hip_runtime.h>

#define B_   8192
#define T_   406
#define D_   10
#define P_   64
#define K0_  4060          // real K (T*D)
#define KE_  4466          // K0 + T (mask/cp2 extension)
#define KP_  4480          // padded K (35 chunks of 128 bf16)
#define NKS_ 8             // K-split across blocks

// output section offsets (floats), reference return order
#define OUT_SEQ   0
#define OUT_IN    (B_*T_*D_)
#define OUT_DIST  (2*B_*T_*D_)
#define OUT_IDX   (OUT_DIST + B_*P_)
#define OUT_LAB   (OUT_IDX + B_)
#define OUT_MASK  (OUT_LAB + B_)

typedef unsigned short ushort_t;
typedef __attribute__((ext_vector_type(8))) short bf16x8;
typedef __attribute__((ext_vector_type(4))) float f32x4;
typedef __attribute__((address_space(3))) unsigned int lds_uint;
typedef __attribute__((address_space(1))) unsigned int glb_uint;

__device__ __forceinline__ void gl_lds16(const void* g, void* l) {
    // async global->LDS, 16B/lane; LDS dest = wave-uniform base + lane*16
    __builtin_amdgcn_global_load_lds((const glb_uint*)g, (lds_uint*)l, 16, 0, 0);
}
__device__ __forceinline__ ushort_t f2bf(float f) {      // f32 -> bf16 RNE
    unsigned u = __float_as_uint(f);
    return (ushort_t)((u + 0x7fffu + ((u >> 16) & 1u)) >> 16);
}

// ---------------- k0: stream x/mask once -> out_in, out_mask, sq_x, bf16 A-blob ----
// axb[row][k'] bf16, rows 8960B; 16B-chunk c stored at position (c&~7)|((c^row)&7)
__global__ __launch_bounds__(256) void k0_prep(
    const float* __restrict__ x, const float* __restrict__ mask,
    ushort_t* __restrict__ axb, float* __restrict__ out_in,
    float* __restrict__ out_mask, float* __restrict__ sq_x)
{
    __shared__ float ms[4][416];
    const int wave = threadIdx.x >> 6, lane = threadIdx.x & 63;
    const int row = blockIdx.x * 4 + wave;
    const float* mrow = mask + (size_t)row * T_;
    float* omrow = out_mask + (size_t)row * T_;
    for (int j = lane; j < T_; j += 64) { float m = mrow[j]; ms[wave][j] = m; omrow[j] = m; }
    // same-wave LDS RAW: compiler orders via lgkmcnt, no barrier needed
    const float4* x4 = (const float4*)(x + (size_t)row * K0_);
    float4* o4 = (float4*)(out_in + (size_t)row * K0_);
    ushort_t* arow = axb + (size_t)row * KP_;
    const int rk = row & 7;
    float sx = 0.f;
    for (int i = lane; i < 1015; i += 64) {
        float4 v = x4[i];
        o4[i] = v;                                        // fused input_seq copy
        int k = 4 * i;
        int t0 = (k*6554)>>16, t1 = ((k+1)*6554)>>16;
        int t2 = ((k+2)*6554)>>16, t3 = ((k+3)*6554)>>16; // k/10 via magic mul
        float a0 = v.x * ms[wave][t0], a1 = v.y * ms[wave][t1];
        float a2 = v.z * ms[wave][t2], a3 = v.w * ms[wave][t3];
        sx += a0*v.x + a1*v.y + a2*v.z + a3*v.w;          // f32 sum m*x^2
        int c = i >> 1;
        int s = (c & ~7) | ((c ^ rk) & 7);                // XOR swizzle (16B chunks)
        ushort4 w; w.x = f2bf(a0); w.y = f2bf(a1); w.z = f2bf(a2); w.w = f2bf(a3);
        *(ushort4*)(arow + s * 8 + (i & 1) * 4) = w;
    }
    // extension k in [4060,4466): mask values (bf16-exact 0/1); [4466,4480): zero pad
    for (int i = 1015 + lane; i < 1120; i += 64) {
        int k = 4 * i;
        ushort4 w;
        w.x = (k     < KE_) ? f2bf(ms[wave][k     - K0_]) : (ushort_t)0;
        w.y = (k + 1 < KE_) ? f2bf(ms[wave][k + 1 - K0_]) : (ushort_t)0;
        w.z = (k + 2 < KE_) ? f2bf(ms[wave][k + 2 - K0_]) : (ushort_t)0;
        w.w = (k + 3 < KE_) ? f2bf(ms[wave][k + 3 - K0_]) : (ushort_t)0;
        int c = i >> 1;
        int s = (c & ~7) | ((c ^ rk) & 7);
        *(ushort4*)(arow + s * 8 + (i & 1) * 4) = w;
    }
#pragma unroll
    for (int off = 32; off >= 1; off >>= 1) sx += __shfl_xor(sx, off, 64);
    if (lane == 0) sq_x[row] = sx;
}

// ---------------- k1: prototypes -> bf16 B-blob [-2c | cp2 | 0], same swizzle ------
__global__ __launch_bounds__(256) void k1_prep(
    const float* __restrict__ protos, ushort_t* __restrict__ bxb)
{
    const int p = blockIdx.x;
    const int rk = p & 7;
    ushort_t* brow = bxb + (size_t)p * KP_;
    for (int t = threadIdx.x; t < T_; t += 256) {
        const float* src = protos + (size_t)p * K0_ + t * 10;
        float s2 = 0.f;
#pragma unroll
        for (int d = 0; d < 10; d++) {
            float c = src[d];
            s2 += c * c;
            int k = t * 10 + d;
            int ch = k >> 3;
            int sw = (ch & ~7) | ((ch ^ rk) & 7);
            brow[sw * 8 + (k & 7)] = f2bf(-2.f * c);
        }
        int k = K0_ + t;
        int ch = k >> 3;
        int sw = (ch & ~7) | ((ch ^ rk) & 7);
        brow[sw * 8 + (k & 7)] = f2bf(s2);
    }
    for (int k = KE_ + (int)threadIdx.x; k < KP_; k += 256) {
        int ch = k >> 3;
        int sw = (ch & ~7) | ((ch ^ rk) & 7);
        brow[sw * 8 + (k & 7)] = 0;
    }
}

// ---------------- k2: bf16 MFMA GEMM, BM=128 BN=64 BK=128, K split 8-way -----------
// grid 512: mb = blk>>3 (M tile), ks = blk&7 (K slice: chunks 5,5,5,4,4,4,4,4 of 35)
__global__ __launch_bounds__(256) void k2_gemm(
    const ushort_t* __restrict__ axb, const ushort_t* __restrict__ bxb,
    float* __restrict__ partial)
{
    __shared__ ushort_t As[128 * 128];   // 32KB, rows packed 256B, pre-swizzled
    __shared__ ushort_t Bs[64 * 128];    // 16KB
    const int tid = threadIdx.x, wave = tid >> 6, lane = tid & 63;
    const int mb = blockIdx.x >> 3, ks = blockIdx.x & 7;
    const int rowBase = mb * 128;
    const int cstart = ks * 4 + (ks < 3 ? ks : 3);
    const int ccnt = (ks < 3) ? 5 : 4;
    const int mh = (wave & 1) * 64;      // wave M offset
    const int nh = (wave >> 1) * 32;     // wave N offset
    const int m16 = lane & 15, q4 = lane >> 4;
    const int srow4 = lane >> 4, scol = lane & 15;   // staging lane split

    f32x4 acc[4][2];
#pragma unroll
    for (int a = 0; a < 4; a++)
#pragma unroll
        for (int bb = 0; bb < 2; bb++) acc[a][bb] = (f32x4)0.f;

    for (int cc = 0; cc < ccnt; cc++) {
        const int ch = cstart + cc;
        __syncthreads();                 // previous tile consumed
        // A: wave stages rows [wave*32, wave*32+32): 8 gl_lds16 (4 rows x 256B each)
#pragma unroll
        for (int j = 0; j < 8; j++) {
            int r = wave * 32 + j * 4 + srow4;
            const ushort_t* g = axb + (size_t)(rowBase + r) * KP_ + (ch * 16 + scol) * 8;
            gl_lds16(g, &As[(wave * 32 + j * 4) * 128]);
        }
        // B: wave stages rows [wave*16, wave*16+16)
#pragma unroll
        for (int j = 0; j < 4; j++) {
            int r = wave * 16 + j * 4 + srow4;
            const ushort_t* g = bxb + (size_t)r * KP_ + (ch * 16 + scol) * 8;
            gl_lds16(g, &Bs[(wave * 16 + j * 4) * 128]);
        }
        __syncthreads();                 // staged tile visible
#pragma unroll
        for (int k4 = 0; k4 < 4; k4++) {
            const int chk = k4 * 4 + q4;                 // logical 16B chunk in tile
            const int sw = (chk & ~7) | ((chk ^ m16) & 7); // XOR unswizzle (row&7 = m16&7)
            bf16x8 af[4], bfr[2];
#pragma unroll
            for (int mt = 0; mt < 4; mt++)
                af[mt] = *(const bf16x8*)&As[(mh + mt * 16 + m16) * 128 + sw * 8];
#pragma unroll
            for (int nt = 0; nt < 2; nt++)
                bfr[nt] = *(const bf16x8*)&Bs[(nh + nt * 16 + m16) * 128 + sw * 8];
#pragma unroll
            for (int mt = 0; mt < 4; mt++)
#pragma unroll
                for (int nt = 0; nt < 2; nt++)
                    acc[mt][nt] = __builtin_amdgcn_mfma_f32_16x16x32_bf16(
                        af[mt], bfr[nt], acc[mt][nt], 0, 0, 0);
        }
    }
    // epilogue: C/D layout col(n)=lane&15, row(m)=(lane>>4)*4+reg  [m89-verified]
#pragma unroll
    for (int mt = 0; mt < 4; mt++)
#pragma unroll
        for (int nt = 0; nt < 2; nt++)
#pragma unroll
            for (int q = 0; q < 4; q++) {
                int gr = rowBase + mh + mt * 16 + q4 * 4 + q;
                int gp = nh + nt * 16 + m16;
                partial[((size_t)ks * B_ + gr) * P_ + gp] = acc[mt][nt][q];
            }
}

// ---------------- k3: reduce partials + sq_x, argmin, gather, scalars --------------
__global__ __launch_bounds__(256) void k3_fin(
    const float* __restrict__ partial, const float* __restrict__ sq_x,
    const float* __restrict__ protos, const int* __restrict__ label,
    float* __restrict__ out)
{
    __shared__ int sidx[4];
    const int tid = threadIdx.x, wave = tid >> 6, lane = tid & 63;
    const int b = blockIdx.x * 4 + wave;
    float v = sq_x[b];
#pragma unroll
    for (int ks = 0; ks < NKS_; ks++)
        v += partial[((size_t)ks * B_ + b) * P_ + lane];
    out[OUT_DIST + (size_t)b * 64 + lane] = v;

    float bv = v; int bi = lane;
#pragma unroll
    for (int off = 32; off >= 1; off >>= 1) {
        float ov = __shfl_xor(bv, off, 64);
        int   oi = __shfl_xor(bi, off, 64);
        if (ov < bv || (ov == bv && oi < bi)) { bv = ov; bi = oi; }
    }
    if (lane == 0) {
        sidx[wave] = bi;
        out[OUT_IDX + b] = (float)bi;
        out[OUT_LAB + b] = (float)label[b];
    }
    __syncthreads();
#pragma unroll
    for (int w2 = 0; w2 < 4; w2++) {
        const int bb = blockIdx.x * 4 + w2;
        const float* src = protos + (size_t)sidx[w2] * (T_ * D_);
        float* dst = out + OUT_SEQ + (size_t)bb * (T_ * D_);
        for (int i = tid; i < 1015; i += 256)
            *(float4*)(dst + 4 * i) = *(const float4*)(src + 4 * i);
    }
}

extern "C" void kernel_launch(void* const* d_in, const int* in_sizes, int n_in,
                              void* d_out, int out_size, void* d_ws, size_t ws_size,
                              hipStream_t stream) {
    const float* x      = (const float*)d_in[0];
    const int*   label  = (const int*)d_in[1];
    const float* mask   = (const float*)d_in[2];
    const float* protos = (const float*)d_in[3];
    float* out = (float*)d_out;
    char*  ws  = (char*)d_ws;

    ushort_t* bxb     = (ushort_t*)(ws);            // 64*4480*2 = 573440 B
    float*    sq_x    = (float*)(ws + 573440);      // 32 KB
    float*    partial = (float*)(ws + 606208);      // 8*8192*64*4 = 16.8 MB
    // A-blob scratch lives in the out_seq region (73.4MB < 133MB); k3 overwrites it
    ushort_t* axb     = (ushort_t*)(out + OUT_SEQ);

    hipLaunchKernelGGL(k0_prep, dim3(B_ / 4), dim3(256), 0, stream,
                       x, mask, axb, out + OUT_IN, out + OUT_MASK, sq_x);
    hipLaunchKernelGGL(k1_prep, dim3(64), dim3(256), 0, stream, protos, bxb);
    hipLaunchKernelGGL(k2_gemm, dim3(512), dim3(256), 0, stream, axb, bxb, partial);
    hipLaunchKernelGGL(k3_fin, dim3(B_ / 4), dim3(256), 0, stream,
                       partial, sq_x, protos, label, out);
}